// Round 3
// baseline (143.743 us; speedup 1.0000x reference)
//
#include <hip/hip_runtime.h>

// PooledSSIMLoss: x,y (16,3,512,512) fp32, 11x11 VALID box filters,
// SSIM map (48,502,502) -> scalar 1 - mean.
//
// R3: 256 threads/block, 2 cols/thread (c0=2t). Vertical running sums in
// registers; horizontal 11-tap via double-buffered LDS H exchange (float2).
// Global loads software-pipelined 2 rows deep (new row r+2, old row r-9).
// Old row (r-11) re-fetched from global (L3-hot) instead of an LDS ring.

#define WIN     11
#define IMG     512
#define OUTW    502            // 512 - 11 + 1
#define SEG     16             // output rows per block
#define NSEG    32             // ceil(502/16)
#define NPLANES 48             // 16*3
#define NPART   (NSEG * NPLANES)   // 1536

#define C1f     (0.01f * 0.01f)
#define C2f     (0.03f * 0.03f)
#define EPSf    1e-8f
#define INV121  (1.0f / 121.0f)

__global__ __launch_bounds__(64) void ssim_zero(double* acc) {
    if (threadIdx.x == 0) acc[0] = 0.0;
}

// mode 0: part[bid] = block sum. mode 1: atomicAdd(part, sum).
__global__ __launch_bounds__(256, 6) void ssim_main(const float* __restrict__ x,
                                                    const float* __restrict__ y,
                                                    double* __restrict__ part,
                                                    int mode) {
    __shared__ float H[2][5][IMG];     // double-buffered V-sum exchange
    __shared__ float wsum[4];

    const int t     = threadIdx.x;       // 0..255
    const int plane = blockIdx.y;        // 0..47
    const int seg   = blockIdx.x;        // 0..31
    const int o0    = seg * SEG;
    const int o1    = (o0 + SEG < OUTW) ? (o0 + SEG) : OUTW;
    const int r0    = o0;
    const int r1    = o1 + WIN - 2;      // <= 511

    const float2* xp2 = (const float2*)(x + (size_t)plane * IMG * IMG);
    const float2* yp2 = (const float2*)(y + (size_t)plane * IMG * IMG);

    const int  c0     = 2 * t;
    const bool active = (t <= 250);      // c0 <= 500

    float Vx[2]  = {0.f, 0.f};
    float Vy[2]  = {0.f, 0.f};
    float Vxx[2] = {0.f, 0.f};
    float Vyy[2] = {0.f, 0.f};
    float Vxy[2] = {0.f, 0.f};

    const float2 z2 = make_float2(0.f, 0.f);
    // software pipeline, depth 2: n0 = row r (use now), n1 = row r+1
    float2 n0x = xp2[(size_t)r0 * 256 + t];
    float2 n0y = yp2[(size_t)r0 * 256 + t];
    float2 n1x = xp2[(size_t)(r0 + 1) * 256 + t];
    float2 n1y = yp2[(size_t)(r0 + 1) * 256 + t];
    float2 o0x = z2, o0y = z2, o1x = z2, o1y = z2;

    float lsum = 0.0f;
    int buf = 0;

    for (int r = r0; r <= r1; ++r) {
        // ---- issue loads for iteration r+2 (consumed 2 iterations later) ----
        float2 nnx = z2, nny = z2, oox = z2, ooy = z2;
        const int rc = r + 2;
        if (rc <= r1) {
            nnx = xp2[(size_t)rc * 256 + t];
            nny = yp2[(size_t)rc * 256 + t];
            if (rc - r0 >= WIN) {                 // iter rc subtracts row rc-11
                oox = xp2[(size_t)(rc - WIN) * 256 + t];
                ooy = yp2[(size_t)(rc - WIN) * 256 + t];
            }
        }

        // ---- vertical running sums ----
        if (r - r0 >= WIN) {
            const float xo[2] = {o0x.x, o0x.y};
            const float yo[2] = {o0y.x, o0y.y};
#pragma unroll
            for (int j = 0; j < 2; ++j) {
                Vx[j] -= xo[j];
                Vy[j] -= yo[j];
                Vxx[j] = fmaf(-xo[j], xo[j], Vxx[j]);
                Vyy[j] = fmaf(-yo[j], yo[j], Vyy[j]);
                Vxy[j] = fmaf(-xo[j], yo[j], Vxy[j]);
            }
        }
        {
            const float xn[2] = {n0x.x, n0x.y};
            const float yn[2] = {n0y.x, n0y.y};
#pragma unroll
            for (int j = 0; j < 2; ++j) {
                Vx[j] += xn[j];
                Vy[j] += yn[j];
                Vxx[j] = fmaf(xn[j], xn[j], Vxx[j]);
                Vyy[j] = fmaf(yn[j], yn[j], Vyy[j]);
                Vxy[j] = fmaf(xn[j], yn[j], Vxy[j]);
            }
        }

        // ---- publish V pairs for the horizontal pass ----
        ((float2*)&H[buf][0][0])[t] = make_float2(Vx[0],  Vx[1]);
        ((float2*)&H[buf][1][0])[t] = make_float2(Vy[0],  Vy[1]);
        ((float2*)&H[buf][2][0])[t] = make_float2(Vxx[0], Vxx[1]);
        ((float2*)&H[buf][3][0])[t] = make_float2(Vyy[0], Vyy[1]);
        ((float2*)&H[buf][4][0])[t] = make_float2(Vxy[0], Vxy[1]);
        __syncthreads();

        // ---- horizontal 11-tap + SSIM for output row r-10 ----
        if (active && r - r0 >= WIN - 1) {
            float h0[5], h1[5];
#pragma unroll
            for (int q = 0; q < 5; ++q) {
                const float2* rp = (const float2*)&H[buf][q][0];
                float2 m1 = rp[t + 1], m2 = rp[t + 2], m3 = rp[t + 3];
                float2 m4 = rp[t + 4], m5 = rp[t + 5];
                float own0, own1;
                switch (q) {
                    case 0: own0 = Vx[0];  own1 = Vx[1];  break;
                    case 1: own0 = Vy[0];  own1 = Vy[1];  break;
                    case 2: own0 = Vxx[0]; own1 = Vxx[1]; break;
                    case 3: own0 = Vyy[0]; own1 = Vyy[1]; break;
                    default:own0 = Vxy[0]; own1 = Vxy[1]; break;
                }
                float s = ((own0 + own1) + (m1.x + m1.y))
                        + ((m2.x + m2.y) + (m3.x + m3.y))
                        + ((m4.x + m4.y) + m5.x);
                h0[q] = s;                       // cols c0 .. c0+10
                h1[q] = s - own0 + m5.y;         // cols c0+1 .. c0+11
            }
#pragma unroll
            for (int j = 0; j < 2; ++j) {
                if (c0 + j < OUTW) {
                    const float* h = j ? h1 : h0;
                    float mux = h[0] * INV121, muy = h[1] * INV121;
                    float ex2 = h[2] * INV121, ey2 = h[3] * INV121;
                    float exy = h[4] * INV121;
                    float mxs = mux * mux, mys = muy * muy, mxy = mux * muy;
                    float sx  = fmaxf(fmaf(-mux, mux, ex2), 0.0f);
                    float sy  = fmaxf(fmaf(-muy, muy, ey2), 0.0f);
                    float sxy = exy - mxy;
                    float num = fmaf(2.0f, mxy, C1f) * fmaf(2.0f, sxy, C2f);
                    float den = fmaf(mxs + mys + C1f, sx + sy + C2f, EPSf);
                    float rr  = __builtin_amdgcn_rcpf(den);
                    rr = rr * (2.0f - den * rr);          // 1 Newton step
                    lsum = fmaf(num, rr, lsum);
                }
            }
        }

        // ---- rotate pipelines ----
        buf ^= 1;
        n0x = n1x; n1x = nnx;  n0y = n1y; n1y = nny;
        o0x = o1x; o1x = oox;  o0y = o1y; o1y = ooy;
    }

    // ---- block reduction ----
#pragma unroll
    for (int off = 32; off > 0; off >>= 1) lsum += __shfl_down(lsum, off, 64);
    const int wid = t >> 6, lane = t & 63;
    if (lane == 0) wsum[wid] = lsum;
    __syncthreads();
    if (t == 0) {
        double bs = (double)((wsum[0] + wsum[1]) + (wsum[2] + wsum[3]));
        if (mode == 0) part[blockIdx.y * NSEG + blockIdx.x] = bs;
        else           atomicAdd(part, bs);
    }
}

__global__ __launch_bounds__(256) void ssim_final(const double* __restrict__ part,
                                                  int n, float* __restrict__ out) {
    __shared__ double s[4];
    double v = 0.0;
    for (int i = threadIdx.x; i < n; i += 256) v += part[i];
#pragma unroll
    for (int off = 32; off > 0; off >>= 1) v += __shfl_down(v, off, 64);
    if ((threadIdx.x & 63) == 0) s[threadIdx.x >> 6] = v;
    __syncthreads();
    if (threadIdx.x == 0) {
        double tot = (s[0] + s[1]) + (s[2] + s[3]);
        const double N = (double)NPLANES * OUTW * OUTW;   // 12,096,192
        out[0] = 1.0f - (float)(tot / N);
    }
}

extern "C" void kernel_launch(void* const* d_in, const int* in_sizes, int n_in,
                              void* d_out, int out_size, void* d_ws, size_t ws_size,
                              hipStream_t stream) {
    const float* x = (const float*)d_in[0];
    const float* y = (const float*)d_in[1];
    float* out = (float*)d_out;
    double* part = (double*)d_ws;

    if (ws_size >= (size_t)NPART * sizeof(double)) {
        ssim_main<<<dim3(NSEG, NPLANES), dim3(256), 0, stream>>>(x, y, part, 0);
        ssim_final<<<dim3(1), dim3(256), 0, stream>>>(part, NPART, out);
    } else {
        ssim_zero<<<dim3(1), dim3(64), 0, stream>>>(part);
        ssim_main<<<dim3(NSEG, NPLANES), dim3(256), 0, stream>>>(x, y, part, 1);
        ssim_final<<<dim3(1), dim3(256), 0, stream>>>(part, 1, out);
    }
}